// Round 2
// baseline (491.951 us; speedup 1.0000x reference)
//
#include <hip/hip_runtime.h>

typedef float floatx4 __attribute__((ext_vector_type(4)));
typedef _Float16 half_t;
typedef _Float16 halfx8 __attribute__((ext_vector_type(8)));
typedef _Float16 halfx4 __attribute__((ext_vector_type(4)));

#define S_LEN 2048
#define HDIM 3584
#define NHEADS 28
#define NKVH 4
#define GRP 7
#define DHEAD 128
#define KVDIM 512   // NKVH*DHEAD

// Async global->LDS, 16B per lane. LDS dest is wave-uniform base + lane*16.
__device__ __forceinline__ void load_lds16(const half_t* g, half_t* l) {
    __builtin_amdgcn_global_load_lds(
        (__attribute__((address_space(1))) void*)(g),
        (__attribute__((address_space(3))) void*)(l), 16, 0, 0);
}

// ---------------------------------------------------------------------------
// fp32 -> f16 conversion for hidden + all weights, one launch.
// ---------------------------------------------------------------------------
__global__ __launch_bounds__(256) void cvt_kernel(
    const float* __restrict__ hidden, const float* __restrict__ Wq,
    const float* __restrict__ Wk, const float* __restrict__ Wv,
    const float* __restrict__ Wo,
    half_t* __restrict__ hh, half_t* __restrict__ wq, half_t* __restrict__ wk,
    half_t* __restrict__ wv, half_t* __restrict__ wo)
{
    int b = blockIdx.x;
    const float* src; half_t* dst; long off;
    if (b < 896)       { src = hidden; dst = hh; off = (long)b * 8192; }
    else if (b < 2464) { src = Wq; dst = wq; off = (long)(b - 896) * 8192; }
    else if (b < 2688) { src = Wk; dst = wk; off = (long)(b - 2464) * 8192; }
    else if (b < 2912) { src = Wv; dst = wv; off = (long)(b - 2688) * 8192; }
    else               { src = Wo; dst = wo; off = (long)(b - 2912) * 8192; }
    #pragma unroll
    for (int i = 0; i < 8; i++) {
        long e = off + i * 1024 + threadIdx.x * 4;
        floatx4 d = *(const floatx4*)&src[e];
        halfx4 h;
        h[0] = (half_t)d[0]; h[1] = (half_t)d[1];
        h[2] = (half_t)d[2]; h[3] = (half_t)d[3];
        *(halfx4*)&dst[e] = h;
    }
}

// ---------------------------------------------------------------------------
// 256x256 tile, BK=64, 8-wave (2Mx4N) 8-phase pipelined f16 GEMM.
// C[m][n] = sum_k A[m][k]*B[n][k] (+bias[n]).
// Per wave: 128x64 output = acc[8][4] 16x16 frags. 16 MFMA per phase.
// LDS: A,B each 2 x (256x64) f16 = 128 KiB total, XOR-swizzled
// (slot ^= row&7) on ds_read; global_load_lds dest is linear, so the
// inverse permutation is applied to the per-lane GLOBAL source address.
// Pipeline: 2 K-tiles per loop iter; each phase stages one region
// (2 x 8KB global_load_lds); s_waitcnt vmcnt(4) only at phases 4 & 8
// (never 0 in the loop). Region staged in phase p was last ds_read
// >= 1 barrier earlier (WAR-safe); vmcnt(4)+barrier at group end
// guarantees the next K-tile fully arrived (RAW-safe).
// Last iter stages 2 garbage tiles: reads stay inside the workspace
// (caller provides a tail pad) and the data is never consumed.
// OUT_MODE: 0 = fp32 row-major, 1 = f16 row-major, 2 = f16 col-major (ldc=M).
// ---------------------------------------------------------------------------
template<int OUT_MODE, bool HAS_BIAS>
__device__ __forceinline__ void gemm256(
    const half_t* __restrict__ A, const half_t* __restrict__ B,
    const float* __restrict__ bias, void* __restrict__ Cp,
    long bm, long bn, long ldc, long lda, int K,
    half_t* As, half_t* Bs)
{
    const int tid    = threadIdx.x;
    const int lane   = tid & 63;
    const int wave   = tid >> 6;     // 0..7
    const int wave_m = wave >> 2;    // 0..1
    const int wave_n = wave & 3;     // 0..3
    const int lrow   = lane & 15;
    const int quad   = lane >> 4;
    const int l7     = lane & 7;     // == lrow & 7
    const int sk0    = quad ^ l7;        // swizzled 16B slot, ks=0
    const int sk1    = (4 | quad) ^ l7;  // swizzled 16B slot, ks=1
    const int aw     = wave_m * 64 + lrow;  // A r' row base
    const int bw     = wave_n * 32 + lrow;  // B r' row base

    // staging: thread t covers LDS row r'=(call base)+(t>>3), 16B slot t&7.
    // LDS(r', s) must hold global k-slot s^(r'&7); (r'&7)==((t>>3)&7) for
    // all calls (call bases are multiples of 64 rows).
    const int slg = (tid & 7) ^ ((tid >> 3) & 7);
    const half_t* pA = &A[(bm + (tid >> 3)) * lda + slg * 8];
    const half_t* pB = &B[(bn + ((tid >= 256) ? 64 : 0) + ((tid >> 3) & 31)) * lda + slg * 8];
    half_t* dA = As + (long)tid * 8;
    half_t* dB = Bs + (long)tid * 8;

    // A LDS row remap: r' = h*128 + c*64 + j  <- logical row c*128 + h*64 + j
    // (h = M-half read by phases with mh==h, interleaved across wave_m bands)
    #define STG_A(PAR,H,KT) do{ \
        const half_t* s_ = pA + (long)(H) * 64 * lda + (long)(KT) * 64; \
        half_t* d_ = dA + (PAR) * 16384 + (H) * 8192; \
        load_lds16(s_, d_); \
        load_lds16(s_ + 128 * lda, d_ + 4096); } while(0)
    // B LDS row remap: r' = h*128 + wn*32 + j <- logical n = wn*64 + h*32 + j
    #define STG_B(PAR,H,KT) do{ \
        const half_t* s_ = pB + (long)(H) * 32 * lda + (long)(KT) * 64; \
        half_t* d_ = dB + (PAR) * 16384 + (H) * 8192; \
        load_lds16(s_, d_); \
        load_lds16(s_ + 128 * lda, d_ + 4096); } while(0)

    #define ARD(PAR,MH,M,KS) \
        (*(const halfx8*)&As[(PAR)*16384 + ((MH)*128 + aw + (M)*16)*64 + ((KS)?sk1:sk0)*8])
    #define BRD(PAR,NH,N2,KS) \
        (*(const halfx8*)&Bs[(PAR)*16384 + ((NH)*128 + bw + (N2)*16)*64 + ((KS)?sk1:sk0)*8])

    #define BAR() asm volatile("s_barrier" ::: "memory")
    #define VMW() asm volatile("s_waitcnt vmcnt(4)" ::: "memory")

    floatx4 acc[8][4] = {};
    halfx8 af[4][2];
    halfx8 bf[2][2];

    #define PHASE(PAR, MH, NH, STGST, DOVM) do { \
        if ((NH) == 0) { \
            _Pragma("unroll") \
            for (int m_ = 0; m_ < 4; m_++) { \
                af[m_][0] = ARD(PAR, MH, m_, 0); \
                af[m_][1] = ARD(PAR, MH, m_, 1); \
            } \
        } \
        _Pragma("unroll") \
        for (int n_ = 0; n_ < 2; n_++) { \
            bf[n_][0] = BRD(PAR, NH, n_, 0); \
            bf[n_][1] = BRD(PAR, NH, n_, 1); \
        } \
        STGST; \
        if (DOVM) VMW(); \
        BAR(); \
        __builtin_amdgcn_s_setprio(1); \
        _Pragma("unroll") \
        for (int ks_ = 0; ks_ < 2; ks_++) \
            _Pragma("unroll") \
            for (int m_ = 0; m_ < 4; m_++) \
                _Pragma("unroll") \
                for (int n_ = 0; n_ < 2; n_++) \
                    acc[(MH)*4 + m_][(NH)*2 + n_] = \
                        __builtin_amdgcn_mfma_f32_16x16x32_f16( \
                            af[m_][ks_], bf[n_][ks_], \
                            acc[(MH)*4 + m_][(NH)*2 + n_], 0, 0, 0); \
        __builtin_amdgcn_s_setprio(0); \
        BAR(); \
    } while(0)

    // prologue: tile0 fully (buf0) + tile1 h0 regions (buf1) = 12 loads;
    // vmcnt(4) -> tile0's 8 loads arrived.
    STG_A(0, 0, 0); STG_B(0, 0, 0); STG_A(0, 1, 0); STG_B(0, 1, 0);
    STG_A(1, 0, 1); STG_B(1, 0, 1);
    VMW(); BAR();

    const int ni = K >> 7;   // 2 K-tiles (BK=64) per iter
    for (int i = 0; i < ni; i++) {
        const int e2 = 2 * i;
        PHASE(0, 0, 0, STG_A(1, 1, e2 + 1), 0);
        PHASE(0, 0, 1, STG_B(1, 1, e2 + 1), 0);
        PHASE(0, 1, 0, STG_A(0, 0, e2 + 2), 0);
        PHASE(0, 1, 1, STG_B(0, 0, e2 + 2), 1);
        PHASE(1, 0, 0, STG_A(0, 1, e2 + 2), 0);
        PHASE(1, 0, 1, STG_B(0, 1, e2 + 2), 0);
        PHASE(1, 1, 0, STG_A(1, 0, e2 + 3), 0);
        PHASE(1, 1, 1, STG_B(1, 0, e2 + 3), 1);
    }

    // Epilogue: C/D layout col=lane&15, row=quad*4+reg
    #pragma unroll
    for (int n = 0; n < 4; n++) {
        long col = bn + wave_n * 64 + n * 16 + lrow;
        float bvv = HAS_BIAS ? bias[col] : 0.0f;
        #pragma unroll
        for (int m = 0; m < 8; m++) {
            long rbase = bm + wave_m * 128 + m * 16 + quad * 4;
            if constexpr (OUT_MODE == 2) {
                halfx4 h;
                #pragma unroll
                for (int r = 0; r < 4; r++)
                    h[r] = (half_t)(acc[m][n][r] + bvv);
                *(halfx4*)&((half_t*)Cp)[col * ldc + rbase] = h;
            } else {
                #pragma unroll
                for (int r = 0; r < 4; r++) {
                    float v = acc[m][n][r] + bvv;
                    if constexpr (OUT_MODE == 1)
                        ((half_t*)Cp)[(rbase + r) * ldc + col] = (half_t)v;
                    else
                        ((float*)Cp)[(rbase + r) * ldc + col] = v;
                }
            }
        }
    }
    #undef STG_A
    #undef STG_B
    #undef ARD
    #undef BRD
    #undef BAR
    #undef VMW
    #undef PHASE
}

// Fused QKV projection: grid (8, 18); x = row-tile, y = col-tile:
// y<14 -> Q, y<16 -> K, else V^T.
__global__ __launch_bounds__(512, 2) void qkv_kernel(
    const half_t* __restrict__ hh,
    const half_t* __restrict__ wq, const float* __restrict__ bq,
    const half_t* __restrict__ wk, const float* __restrict__ bk,
    const half_t* __restrict__ wv, const float* __restrict__ bv,
    half_t* __restrict__ q, half_t* __restrict__ k, half_t* __restrict__ vt)
{
    __shared__ __align__(16) half_t As[2 * 16384];
    __shared__ __align__(16) half_t Bs[2 * 16384];
    int by = blockIdx.y;
    long bm = (long)blockIdx.x * 256;
    if (by < 14) {
        gemm256<1, true>(hh, wq, bq, q, bm, (long)by * 256, HDIM, HDIM, HDIM, As, Bs);
    } else if (by < 16) {
        gemm256<1, true>(hh, wk, bk, k, bm, (long)(by - 14) * 256, KVDIM, HDIM, HDIM, As, Bs);
    } else {
        gemm256<2, true>(hh, wv, bv, vt, bm, (long)(by - 16) * 256, S_LEN, HDIM, HDIM, As, Bs);
    }
}

// Output projection: out = o @ Wo^T (fp32 out). grid (8, 14).
__global__ __launch_bounds__(512, 2) void oproj_kernel(
    const half_t* __restrict__ o, const half_t* __restrict__ wo,
    float* __restrict__ out)
{
    __shared__ __align__(16) half_t As[2 * 16384];
    __shared__ __align__(16) half_t Bs[2 * 16384];
    gemm256<0, false>(o, wo, nullptr, out,
                      (long)blockIdx.x * 256, (long)blockIdx.y * 256,
                      HDIM, HDIM, HDIM, As, Bs);
}

// In-place RoPE on q (with 1/sqrt(D) scale folded in) and k.
__global__ __launch_bounds__(256) void rope_kernel(
    half_t* __restrict__ q, half_t* __restrict__ k,
    const float* __restrict__ ct, const float* __restrict__ st)
{
    const float scale = 0.08838834764831845f; // 128^-0.5
    int idx = blockIdx.x * 256 + threadIdx.x;
    const int QP = S_LEN * NHEADS * 64;
    half_t* base; int s, d; float sc;
    if (idx < QP) {
        s = idx / (NHEADS * 64);
        int rem = idx % (NHEADS * 64);
        int h = rem >> 6; d = rem & 63;
        base = q + (long)s * HDIM + h * 128 + d;
        sc = scale;
    } else {
        int j = idx - QP;
        s = j / (NKVH * 64);
        int rem = j % (NKVH * 64);
        int h = rem >> 6; d = rem & 63;
        base = k + (long)s * KVDIM + h * 128 + d;
        sc = 1.0f;
    }
    float c = ct[s * 128 + d], sn = st[s * 128 + d];
    float x1 = (float)base[0], x2 = (float)base[64];
    base[0]  = (half_t)((x1 * c - x2 * sn) * sc);
    base[64] = (half_t)((x2 * c + x1 * sn) * sc);
}

// Flash attention, barrier-free. Block = (64 q rows, 1 head), 4 independent
// waves x 16 rows. 64-key chunks; K and V^T fragments loaded directly from
// global (L2-resident); only the per-wave P C->A roundtrip uses LDS.
__global__ __launch_bounds__(256) void attn_kernel(
    const half_t* __restrict__ q, const half_t* __restrict__ k,
    const half_t* __restrict__ vt, const int* __restrict__ doc,
    half_t* __restrict__ o)
{
    constexpr int PS = 72; // 64 keys + 8 pad
    __shared__ half_t Ps[4][16 * PS];

    const int tid  = threadIdx.x;
    const int lane = tid & 63;
    const int wave = tid >> 6;
    const int head = blockIdx.y;
    const int kvh  = head / GRP;
    const int qbase = blockIdx.x * 64;
    const int lrow = lane & 15;
    const int quad = lane >> 4;
    const int k0 = quad * 8;

    const int qrow = qbase + wave * 16 + lrow;
    halfx8 qf[4];
    #pragma unroll
    for (int kk = 0; kk < 4; kk++)
        qf[kk] = *(const halfx8*)&q[(long)qrow * HDIM + head * 128 + kk * 32 + k0];

    int qdoc[4], qpos[4];
    #pragma unroll
    for (int r = 0; r < 4; r++) {
        qpos[r] = qbase + wave * 16 + quad * 4 + r;
        qdoc[r] = doc[qpos[r]];
    }

    // lower_bound(doc, doc[qbase]): skip keys before this tile's earliest doc
    int tgt = doc[qbase];
    int lo = 0, hi = qbase;
    while (lo < hi) { int mid = (lo + hi) >> 1; if (doc[mid] < tgt) lo = mid + 1; else hi = mid; }
    const int kc0 = lo & ~63;

    float m_r[4], l_r[4];
    floatx4 oacc[8] = {};
    #pragma unroll
    for (int r = 0; r < 4; r++) { m_r[r] = -INFINITY; l_r[r] = 0.0f; }

    for (int kbase = kc0; kbase <= qbase; kbase += 64) {
        floatx4 sacc[4] = {};
        #pragma unroll
        for (int s = 0; s < 4; s++) {
            const half_t* kp = &k[(long)(kbase + s * 16 + lrow) * KVDIM + kvh * 128];
            #pragma unroll
            for (int kk = 0; kk < 4; kk++) {
                halfx8 bk = *(const halfx8*)&kp[kk * 32 + k0];
                sacc[s] = __builtin_amdgcn_mfma_f32_16x16x32_f16(qf[kk], bk, sacc[s], 0, 0, 0);
            }
        }

        int kpix[4], kd[4];
        #pragma unroll
        for (int s = 0; s < 4; s++) {
            kpix[s] = kbase + s * 16 + lrow;
            kd[s] = doc[kpix[s]];
        }
        float pk[4][4];
        float alpha[4];
        #pragma unroll
        for (int r = 0; r < 4; r++) {
            float sv[4];
            float mx = -INFINITY;
            #pragma unroll
            for (int s = 0; s < 4; s++) {
                float x = sacc[s][r];
                bool valid = (kpix[s] <= qpos[r]) && (kd[s] == qdoc[r]);
                x = valid ? x : -INFINITY;
                sv[s] = x;
                mx = fmaxf(mx, x);
            }
            #pragma unroll
            for (int off = 1; off < 16; off <<= 1)
                mx = fmaxf(mx, __shfl_xor(mx, off));
            float mnew = fmaxf(m_r[r], mx);
            bool ninf = (mnew != -INFINITY);
            alpha[r] = ninf ? __expf(m_r[r] - mnew) : 1.0f;
            float sm = 0.0f;
            #pragma unroll
            for (int s = 0; s < 4; s++) {
                float p = ninf ? __expf(sv[s] - mnew) : 0.0f;
                pk[s][r] = p;
                sm += p;
            }
            #pragma unroll
            for (int off = 1; off < 16; off <<= 1)
                sm += __shfl_xor(sm, off);
            l_r[r] = l_r[r] * alpha[r] + sm;
            m_r[r] = mnew;
        }

        #pragma unroll
        for (int t = 0; t < 8; t++)
            #pragma unroll
            for (int r = 0; r < 4; r++)
                oacc[t][r] *= alpha[r];

        #pragma unroll
        for (int s = 0; s < 4; s++)
            #pragma unroll
            for (int r = 0; r < 4; r++)
                Ps[wave][(quad * 4 + r) * PS + s * 16 + lrow] = (half_t)pk[s][r];
        halfx8 pa0 = *(const halfx8*)&Ps[wave][lrow * PS + k0];
        halfx8 pa1 = *(const halfx8*)&Ps[wave][lrow * PS + 32 + k0];

        #pragma unroll
        for (int t = 0; t < 8; t++) {
            const half_t* vp = &vt[(long)(kvh * 128 + t * 16 + lrow) * S_LEN + kbase];
            halfx8 b0 = *(const halfx8*)&vp[k0];
            halfx8 b1 = *(const halfx8*)&vp[32 + k0];
            oacc[t] = __builtin_amdgcn_mfma_f32_16x16x32_f16(pa0, b0, oacc[t], 0, 0, 0);
            oacc[t] = __builtin_amdgcn_mfma_f32_16x16x32_f16(pa1, b1, oacc[t], 0, 0, 0);
        }
    }

    #pragma unroll
    for (int r = 0; r < 4; r++) {
        float inv = 1.0f / l_r[r];
        long row = qpos[r];
        #pragma unroll
        for (int t = 0; t < 8; t++)
            o[row * HDIM + head * 128 + t * 16 + lrow] = (half_t)(oacc[t][r] * inv);
    }
}

extern "C" void kernel_launch(void* const* d_in, const int* in_sizes, int n_in,
                              void* d_out, int out_size, void* d_ws, size_t ws_size,
                              hipStream_t stream) {
    const float* hidden = (const float*)d_in[0];
    const float* cosT   = (const float*)d_in[1];
    const float* sinT   = (const float*)d_in[2];
    const int*   doc    = (const int*)d_in[3];
    // d_in[4] = position_ids (unused; cos/sin precomputed)
    const float* Wq = (const float*)d_in[5];
    const float* bq = (const float*)d_in[6];
    const float* Wk = (const float*)d_in[7];
    const float* bk = (const float*)d_in[8];
    const float* Wv = (const float*)d_in[9];
    const float* bv = (const float*)d_in[10];
    const float* Wo = (const float*)d_in[11];
    float* out = (float*)d_out;

    // f16 workspace layout (halves); ~92 MB + tail pad (the GEMM pipeline
    // prefetches 2 garbage K-tiles past the end of the last operand).
    half_t* hh  = (half_t*)d_ws;                   // dead after qkv; o reuses it
    half_t* q   = hh  + (size_t)S_LEN * HDIM;
    half_t* k   = q   + (size_t)S_LEN * HDIM;
    half_t* vt  = k   + (size_t)S_LEN * KVDIM;
    half_t* woh = vt  + (size_t)KVDIM * S_LEN;
    half_t* wqh = woh + (size_t)HDIM * HDIM;
    half_t* wkh = wqh + (size_t)HDIM * HDIM;
    half_t* wvh = wkh + (size_t)KVDIM * HDIM;      // followed by pad
    half_t* o   = hh; // alias: hh is dead once qkv_kernel completes

    cvt_kernel<<<4480, 256, 0, stream>>>(hidden, Wq, Wk, Wv, Wo, hh, wqh, wkh, wvh, woh);
    qkv_kernel<<<dim3(8, 18), 512, 0, stream>>>(hh, wqh, bq, wkh, bk, wvh, bv, q, k, vt);
    rope_kernel<<<16384, 256, 0, stream>>>(q, k, cosT, sinT);
    attn_kernel<<<dim3(32, NHEADS), 256, 0, stream>>>(q, k, vt, doc, o);
    oproj_kernel<<<dim3(8, 14), 512, 0, stream>>>(o, woh, out);
}

// Round 3
// 454.307 us; speedup vs baseline: 1.0829x; 1.0829x over previous
//
#include <hip/hip_runtime.h>

typedef float floatx4 __attribute__((ext_vector_type(4)));
typedef _Float16 half_t;
typedef _Float16 halfx8 __attribute__((ext_vector_type(8)));
typedef _Float16 halfx4 __attribute__((ext_vector_type(4)));

#define S_LEN 2048
#define HDIM 3584
#define NHEADS 28
#define NKVH 4
#define GRP 7
#define DHEAD 128
#define KVDIM 512   // NKVH*DHEAD
#define KHALF 1792  // HDIM/2 (oproj split-K)

// Async global->LDS, 16B per lane. LDS dest is wave-uniform base + lane*16.
__device__ __forceinline__ void load_lds16(const half_t* g, half_t* l) {
    __builtin_amdgcn_global_load_lds(
        (__attribute__((address_space(1))) void*)(g),
        (__attribute__((address_space(3))) void*)(l), 16, 0, 0);
}

// ---------------------------------------------------------------------------
// fp32 -> f16 conversion for hidden + all weights, one launch.
// ---------------------------------------------------------------------------
__global__ __launch_bounds__(256) void cvt_kernel(
    const float* __restrict__ hidden, const float* __restrict__ Wq,
    const float* __restrict__ Wk, const float* __restrict__ Wv,
    const float* __restrict__ Wo,
    half_t* __restrict__ hh, half_t* __restrict__ wq, half_t* __restrict__ wk,
    half_t* __restrict__ wv, half_t* __restrict__ wo)
{
    int b = blockIdx.x;
    const float* src; half_t* dst; long off;
    if (b < 896)       { src = hidden; dst = hh; off = (long)b * 8192; }
    else if (b < 2464) { src = Wq; dst = wq; off = (long)(b - 896) * 8192; }
    else if (b < 2688) { src = Wk; dst = wk; off = (long)(b - 2464) * 8192; }
    else if (b < 2912) { src = Wv; dst = wv; off = (long)(b - 2688) * 8192; }
    else               { src = Wo; dst = wo; off = (long)(b - 2912) * 8192; }
    #pragma unroll
    for (int i = 0; i < 8; i++) {
        long e = off + i * 1024 + threadIdx.x * 4;
        floatx4 d = *(const floatx4*)&src[e];
        halfx4 h;
        h[0] = (half_t)d[0]; h[1] = (half_t)d[1];
        h[2] = (half_t)d[2]; h[3] = (half_t)d[3];
        *(halfx4*)&dst[e] = h;
    }
}

// ---------------------------------------------------------------------------
// 256x256 tile, BK=64, 8-wave (2Mx4N) 8-phase pipelined f16 GEMM.
// C[m][n] = sum_k A[m][k]*B[n][k] (+bias[n]).
// LDS: A,B each 2 x (256x64) f16 = 128 KiB, XOR-swizzled (slot ^= row&7) on
// ds_read; global_load_lds dest is linear -> inverse permutation applied to
// the per-lane GLOBAL source address.
//
// Deep-prefetch schedule (each region staged at its EARLIEST WAR-safe phase
// so the worst issue->wait distance is 3 phases ~ >= HBM latency):
//   reads (iter i): p1 A0h0,B0h0 | p2 B0h1 | p3 A0h1,B0h0 | p4 B0h1
//                   p5 A1h0,B1h0 | p6 B1h1 | p7 A1h1,B1h0 | p8 B1h1
//   stages:  p1: A1h1,B1h1 <- T(2i+1)   (last read of old: p7/p8 of i-1)
//            p2: A0h0 <- T(2i+2)        (old last read p1)
//            p4: B0h0,A0h1 <- T(2i+2)   (old last read p3) + vmcnt(6)
//            p5: B0h1 <- T(2i+2)        (old last read p4)
//            p7: A1h0 <- T(2i+3)        (old last read p5)
//            p8: B1h0 <- T(2i+3)        (old last read p7) + vmcnt(4)
//   vmcnt(6)@p4: 6 newest outstanding = p4(4)+p2(2) -> waits exactly
//     {p7,p8 of i-1, p1} = all of T(2i+1); issue distance >= 3 phases.
//   vmcnt(4)@p8: 4 newest = p7(2)+p8(2) -> waits {p2,p4,p5} = all of
//     T(2i+2); distance >= 3 phases.
// Last iter stages 2 garbage tiles (reads stay in workspace tail; never
// consumed).
// OUT_MODE: 0 = fp32 row-major, 1 = f16 row-major, 2 = f16 col-major (ldc=M).
// ---------------------------------------------------------------------------
template<int OUT_MODE, bool HAS_BIAS>
__device__ __forceinline__ void gemm256(
    const half_t* __restrict__ A, const half_t* __restrict__ B,
    const float* __restrict__ bias, void* __restrict__ Cp,
    long bm, long bn, long ldc, long lda, int K,
    half_t* As, half_t* Bs)
{
    const int tid    = threadIdx.x;
    const int lane   = tid & 63;
    const int wave   = tid >> 6;     // 0..7
    const int wave_m = wave >> 2;    // 0..1
    const int wave_n = wave & 3;     // 0..3
    const int lrow   = lane & 15;
    const int quad   = lane >> 4;
    const int l7     = lane & 7;     // == lrow & 7
    const int sk0    = quad ^ l7;        // swizzled 16B slot, ks=0
    const int sk1    = (4 | quad) ^ l7;  // swizzled 16B slot, ks=1
    const int aw     = wave_m * 64 + lrow;  // A r' row base
    const int bw     = wave_n * 32 + lrow;  // B r' row base

    // staging: thread t covers LDS row r'=(call base)+(t>>3), 16B slot t&7.
    // LDS(r', s) must hold global k-slot s^(r'&7).
    const int slg = (tid & 7) ^ ((tid >> 3) & 7);
    const half_t* pA = &A[(bm + (tid >> 3)) * lda + slg * 8];
    const half_t* pB = &B[(bn + ((tid >= 256) ? 64 : 0) + ((tid >> 3) & 31)) * lda + slg * 8];
    half_t* dA = As + (long)tid * 8;
    half_t* dB = Bs + (long)tid * 8;

    #define STG_A(PAR,H,KT) do{ \
        const half_t* s_ = pA + (long)(H) * 64 * lda + (long)(KT) * 64; \
        half_t* d_ = dA + (PAR) * 16384 + (H) * 8192; \
        load_lds16(s_, d_); \
        load_lds16(s_ + 128 * lda, d_ + 4096); } while(0)
    #define STG_B(PAR,H,KT) do{ \
        const half_t* s_ = pB + (long)(H) * 32 * lda + (long)(KT) * 64; \
        half_t* d_ = dB + (PAR) * 16384 + (H) * 8192; \
        load_lds16(s_, d_); \
        load_lds16(s_ + 128 * lda, d_ + 4096); } while(0)

    #define ARD(PAR,MH,M,KS) \
        (*(const halfx8*)&As[(PAR)*16384 + ((MH)*128 + aw + (M)*16)*64 + ((KS)?sk1:sk0)*8])
    #define BRD(PAR,NH,N2,KS) \
        (*(const halfx8*)&Bs[(PAR)*16384 + ((NH)*128 + bw + (N2)*16)*64 + ((KS)?sk1:sk0)*8])

    #define BAR() asm volatile("s_barrier" ::: "memory")
    #define VMW4() asm volatile("s_waitcnt vmcnt(4)" ::: "memory")
    #define VMW6() asm volatile("s_waitcnt vmcnt(6)" ::: "memory")

    floatx4 acc[8][4] = {};
    halfx8 af[4][2];
    halfx8 bf[2][2];

    #define PHASE(PAR, MH, NH, STGST) do { \
        if ((NH) == 0) { \
            _Pragma("unroll") \
            for (int m_ = 0; m_ < 4; m_++) { \
                af[m_][0] = ARD(PAR, MH, m_, 0); \
                af[m_][1] = ARD(PAR, MH, m_, 1); \
            } \
        } \
        _Pragma("unroll") \
        for (int n_ = 0; n_ < 2; n_++) { \
            bf[n_][0] = BRD(PAR, NH, n_, 0); \
            bf[n_][1] = BRD(PAR, NH, n_, 1); \
        } \
        STGST; \
        BAR(); \
        __builtin_amdgcn_s_setprio(1); \
        _Pragma("unroll") \
        for (int ks_ = 0; ks_ < 2; ks_++) \
            _Pragma("unroll") \
            for (int m_ = 0; m_ < 4; m_++) \
                _Pragma("unroll") \
                for (int n_ = 0; n_ < 2; n_++) \
                    acc[(MH)*4 + m_][(NH)*2 + n_] = \
                        __builtin_amdgcn_mfma_f32_16x16x32_f16( \
                            af[m_][ks_], bf[n_][ks_], \
                            acc[(MH)*4 + m_][(NH)*2 + n_], 0, 0, 0); \
        __builtin_amdgcn_s_setprio(0); \
        BAR(); \
    } while(0)

    // prologue: T0 fully (8 loads) + T1 h0 regions (4 loads);
    // vmcnt(4) -> T0's 8 loads arrived.
    STG_A(0, 0, 0); STG_B(0, 0, 0); STG_A(0, 1, 0); STG_B(0, 1, 0);
    STG_A(1, 0, 1); STG_B(1, 0, 1);
    VMW4(); BAR();

    const int ni = K >> 7;   // 2 K-tiles (BK=64) per iter
    for (int i = 0; i < ni; i++) {
        const int e2 = 2 * i;
        PHASE(0, 0, 0, STG_A(1, 1, e2 + 1); STG_B(1, 1, e2 + 1));
        PHASE(0, 0, 1, STG_A(0, 0, e2 + 2));
        PHASE(0, 1, 0, (void)0);
        PHASE(0, 1, 1, STG_B(0, 0, e2 + 2); STG_A(0, 1, e2 + 2); VMW6());
        PHASE(1, 0, 0, STG_B(0, 1, e2 + 2));
        PHASE(1, 0, 1, (void)0);
        PHASE(1, 1, 0, STG_A(1, 0, e2 + 3));
        PHASE(1, 1, 1, STG_B(1, 0, e2 + 3); VMW4());
    }

    // Epilogue: C/D layout col=lane&15, row=quad*4+reg
    #pragma unroll
    for (int n = 0; n < 4; n++) {
        long col = bn + wave_n * 64 + n * 16 + lrow;
        float bvv = HAS_BIAS ? bias[col] : 0.0f;
        #pragma unroll
        for (int m = 0; m < 8; m++) {
            long rbase = bm + wave_m * 128 + m * 16 + quad * 4;
            if constexpr (OUT_MODE == 2) {
                halfx4 h;
                #pragma unroll
                for (int r = 0; r < 4; r++)
                    h[r] = (half_t)(acc[m][n][r] + bvv);
                *(halfx4*)&((half_t*)Cp)[col * ldc + rbase] = h;
            } else {
                #pragma unroll
                for (int r = 0; r < 4; r++) {
                    float v = acc[m][n][r] + bvv;
                    if constexpr (OUT_MODE == 1)
                        ((half_t*)Cp)[(rbase + r) * ldc + col] = (half_t)v;
                    else
                        ((float*)Cp)[(rbase + r) * ldc + col] = v;
                }
            }
        }
    }
    #undef STG_A
    #undef STG_B
    #undef ARD
    #undef BRD
    #undef BAR
    #undef VMW4
    #undef VMW6
    #undef PHASE
}

// Fused QKV projection: grid (8, 18); x = row-tile, y = col-tile:
// y<14 -> Q, y<16 -> K, else V^T.
__global__ __launch_bounds__(512, 2) void qkv_kernel(
    const half_t* __restrict__ hh,
    const half_t* __restrict__ wq, const float* __restrict__ bq,
    const half_t* __restrict__ wk, const float* __restrict__ bk,
    const half_t* __restrict__ wv, const float* __restrict__ bv,
    half_t* __restrict__ q, half_t* __restrict__ k, half_t* __restrict__ vt)
{
    __shared__ __align__(16) half_t As[2 * 16384];
    __shared__ __align__(16) half_t Bs[2 * 16384];
    int by = blockIdx.y;
    long bm = (long)blockIdx.x * 256;
    if (by < 14) {
        gemm256<1, true>(hh, wq, bq, q, bm, (long)by * 256, HDIM, HDIM, HDIM, As, Bs);
    } else if (by < 16) {
        gemm256<1, true>(hh, wk, bk, k, bm, (long)(by - 14) * 256, KVDIM, HDIM, HDIM, As, Bs);
    } else {
        gemm256<2, true>(hh, wv, bv, vt, bm, (long)(by - 16) * 256, S_LEN, HDIM, HDIM, As, Bs);
    }
}

// Output projection, split-K=2: out_partial[z] = o[:,zK:] @ Wo[:,zK:]^T.
// grid (8, 14, 2); f16 partials (aliased over dead wq/wk/wv region).
__global__ __launch_bounds__(512, 2) void oproj_kernel(
    const half_t* __restrict__ o, const half_t* __restrict__ wo,
    half_t* __restrict__ Po)
{
    __shared__ __align__(16) half_t As[2 * 16384];
    __shared__ __align__(16) half_t Bs[2 * 16384];
    int z = blockIdx.z;
    long koff = (long)z * KHALF;
    gemm256<1, false>(o + koff, wo + koff, nullptr,
                      Po + (size_t)z * S_LEN * HDIM,
                      (long)blockIdx.x * 256, (long)blockIdx.y * 256,
                      HDIM, HDIM, KHALF, As, Bs);
}

// Sum the two f16 oproj partials into the final fp32 output.
__global__ __launch_bounds__(256) void oreduce_kernel(
    const half_t* __restrict__ Po, float* __restrict__ out)
{
    long i = ((long)blockIdx.x * 256 + threadIdx.x) * 4;
    halfx4 a = *(const halfx4*)&Po[i];
    halfx4 b = *(const halfx4*)&Po[(size_t)S_LEN * HDIM + i];
    floatx4 r;
    #pragma unroll
    for (int j = 0; j < 4; j++)
        r[j] = (float)a[j] + (float)b[j];
    *(floatx4*)&out[i] = r;
}

// In-place RoPE on q (with 1/sqrt(D) scale folded in) and k.
__global__ __launch_bounds__(256) void rope_kernel(
    half_t* __restrict__ q, half_t* __restrict__ k,
    const float* __restrict__ ct, const float* __restrict__ st)
{
    const float scale = 0.08838834764831845f; // 128^-0.5
    int idx = blockIdx.x * 256 + threadIdx.x;
    const int QP = S_LEN * NHEADS * 64;
    half_t* base; int s, d; float sc;
    if (idx < QP) {
        s = idx / (NHEADS * 64);
        int rem = idx % (NHEADS * 64);
        int h = rem >> 6; d = rem & 63;
        base = q + (long)s * HDIM + h * 128 + d;
        sc = scale;
    } else {
        int j = idx - QP;
        s = j / (NKVH * 64);
        int rem = j % (NKVH * 64);
        int h = rem >> 6; d = rem & 63;
        base = k + (long)s * KVDIM + h * 128 + d;
        sc = 1.0f;
    }
    float c = ct[s * 128 + d], sn = st[s * 128 + d];
    float x1 = (float)base[0], x2 = (float)base[64];
    base[0]  = (half_t)((x1 * c - x2 * sn) * sc);
    base[64] = (half_t)((x2 * c + x1 * sn) * sc);
}

// Flash attention, barrier-free. Block = (64 q rows, 1 head), 4 independent
// waves x 16 rows. 64-key chunks; K and V^T fragments loaded directly from
// global (L2-resident); only the per-wave P C->A roundtrip uses LDS.
__global__ __launch_bounds__(256) void attn_kernel(
    const half_t* __restrict__ q, const half_t* __restrict__ k,
    const half_t* __restrict__ vt, const int* __restrict__ doc,
    half_t* __restrict__ o)
{
    constexpr int PS = 72; // 64 keys + 8 pad
    __shared__ half_t Ps[4][16 * PS];

    const int tid  = threadIdx.x;
    const int lane = tid & 63;
    const int wave = tid >> 6;
    const int head = blockIdx.y;
    const int kvh  = head / GRP;
    const int qbase = blockIdx.x * 64;
    const int lrow = lane & 15;
    const int quad = lane >> 4;
    const int k0 = quad * 8;

    const int qrow = qbase + wave * 16 + lrow;
    halfx8 qf[4];
    #pragma unroll
    for (int kk = 0; kk < 4; kk++)
        qf[kk] = *(const halfx8*)&q[(long)qrow * HDIM + head * 128 + kk * 32 + k0];

    int qdoc[4], qpos[4];
    #pragma unroll
    for (int r = 0; r < 4; r++) {
        qpos[r] = qbase + wave * 16 + quad * 4 + r;
        qdoc[r] = doc[qpos[r]];
    }

    // lower_bound(doc, doc[qbase]): skip keys before this tile's earliest doc
    int tgt = doc[qbase];
    int lo = 0, hi = qbase;
    while (lo < hi) { int mid = (lo + hi) >> 1; if (doc[mid] < tgt) lo = mid + 1; else hi = mid; }
    const int kc0 = lo & ~63;

    float m_r[4], l_r[4];
    floatx4 oacc[8] = {};
    #pragma unroll
    for (int r = 0; r < 4; r++) { m_r[r] = -INFINITY; l_r[r] = 0.0f; }

    for (int kbase = kc0; kbase <= qbase; kbase += 64) {
        floatx4 sacc[4] = {};
        #pragma unroll
        for (int s = 0; s < 4; s++) {
            const half_t* kp = &k[(long)(kbase + s * 16 + lrow) * KVDIM + kvh * 128];
            #pragma unroll
            for (int kk = 0; kk < 4; kk++) {
                halfx8 bk = *(const halfx8*)&kp[kk * 32 + k0];
                sacc[s] = __builtin_amdgcn_mfma_f32_16x16x32_f16(qf[kk], bk, sacc[s], 0, 0, 0);
            }
        }

        int kpix[4], kd[4];
        #pragma unroll
        for (int s = 0; s < 4; s++) {
            kpix[s] = kbase + s * 16 + lrow;
            kd[s] = doc[kpix[s]];
        }
        float pk[4][4];
        float alpha[4];
        #pragma unroll
        for (int r = 0; r < 4; r++) {
            float sv[4];
            float mx = -INFINITY;
            #pragma unroll
            for (int s = 0; s < 4; s++) {
                float x = sacc[s][r];
                bool valid = (kpix[s] <= qpos[r]) && (kd[s] == qdoc[r]);
                x = valid ? x : -INFINITY;
                sv[s] = x;
                mx = fmaxf(mx, x);
            }
            #pragma unroll
            for (int off = 1; off < 16; off <<= 1)
                mx = fmaxf(mx, __shfl_xor(mx, off));
            float mnew = fmaxf(m_r[r], mx);
            bool ninf = (mnew != -INFINITY);
            alpha[r] = ninf ? __expf(m_r[r] - mnew) : 1.0f;
            float sm = 0.0f;
            #pragma unroll
            for (int s = 0; s < 4; s++) {
                float p = ninf ? __expf(sv[s] - mnew) : 0.0f;
                pk[s][r] = p;
                sm += p;
            }
            #pragma unroll
            for (int off = 1; off < 16; off <<= 1)
                sm += __shfl_xor(sm, off);
            l_r[r] = l_r[r] * alpha[r] + sm;
            m_r[r] = mnew;
        }

        #pragma unroll
        for (int t = 0; t < 8; t++)
            #pragma unroll
            for (int r = 0; r < 4; r++)
                oacc[t][r] *= alpha[r];

        #pragma unroll
        for (int s = 0; s < 4; s++)
            #pragma unroll
            for (int r = 0; r < 4; r++)
                Ps[wave][(quad * 4 + r) * PS + s * 16 + lrow] = (half_t)pk[s][r];
        halfx8 pa0 = *(const halfx8*)&Ps[wave][lrow * PS + k0];
        halfx8 pa1 = *(const halfx8*)&Ps[wave][lrow * PS + 32 + k0];

        #pragma unroll
        for (int t = 0; t < 8; t++) {
            const half_t* vp = &vt[(long)(kvh * 128 + t * 16 + lrow) * S_LEN + kbase];
            halfx8 b0 = *(const halfx8*)&vp[k0];
            halfx8 b1 = *(const halfx8*)&vp[32 + k0];
            oacc[t] = __builtin_amdgcn_mfma_f32_16x16x32_f16(pa0, b0, oacc[t], 0, 0, 0);
            oacc[t] = __builtin_amdgcn_mfma_f32_16x16x32_f16(pa1, b1, oacc[t], 0, 0, 0);
        }
    }

    #pragma unroll
    for (int r = 0; r < 4; r++) {
        float inv = 1.0f / l_r[r];
        long row = qpos[r];
        #pragma unroll
        for (int t = 0; t < 8; t++)
            o[row * HDIM + head * 128 + t * 16 + lrow] = (half_t)(oacc[t][r] * inv);
    }
}

extern "C" void kernel_launch(void* const* d_in, const int* in_sizes, int n_in,
                              void* d_out, int out_size, void* d_ws, size_t ws_size,
                              hipStream_t stream) {
    const float* hidden = (const float*)d_in[0];
    const float* cosT   = (const float*)d_in[1];
    const float* sinT   = (const float*)d_in[2];
    const int*   doc    = (const int*)d_in[3];
    // d_in[4] = position_ids (unused; cos/sin precomputed)
    const float* Wq = (const float*)d_in[5];
    const float* bq = (const float*)d_in[6];
    const float* Wk = (const float*)d_in[7];
    const float* bk = (const float*)d_in[8];
    const float* Wv = (const float*)d_in[9];
    const float* bv = (const float*)d_in[10];
    const float* Wo = (const float*)d_in[11];
    float* out = (float*)d_out;

    // f16 workspace layout (halves); ~93 MB + tail pad (the GEMM pipeline
    // prefetches 2 garbage K-tiles past the end of the last operand).
    // Po (oproj f16 partials, 14.7M halves) aliases wqh..wvh (16.5M halves,
    // dead at oproj time). woh is placed before wqh so it stays live.
    half_t* hh  = (half_t*)d_ws;                   // dead after qkv; o reuses it
    half_t* q   = hh  + (size_t)S_LEN * HDIM;
    half_t* k   = q   + (size_t)S_LEN * HDIM;
    half_t* vt  = k   + (size_t)S_LEN * KVDIM;
    half_t* woh = vt  + (size_t)KVDIM * S_LEN;
    half_t* wqh = woh + (size_t)HDIM * HDIM;
    half_t* wkh = wqh + (size_t)HDIM * HDIM;
    half_t* wvh = wkh + (size_t)KVDIM * HDIM;      // followed by tail pad
    half_t* o   = hh;            // alias: hh dead once qkv_kernel completes
    half_t* Po  = wqh;           // alias: weights dead at oproj time

    cvt_kernel<<<4480, 256, 0, stream>>>(hidden, Wq, Wk, Wv, Wo, hh, wqh, wkh, wvh, woh);
    qkv_kernel<<<dim3(8, 18), 512, 0, stream>>>(hh, wqh, bq, wkh, bk, wvh, bv, q, k, vt);
    rope_kernel<<<16384, 256, 0, stream>>>(q, k, cosT, sinT);
    attn_kernel<<<dim3(32, NHEADS), 256, 0, stream>>>(q, k, vt, doc, o);
    oproj_kernel<<<dim3(8, 14, 2), 512, 0, stream>>>(o, woh, Po);
    oreduce_kernel<<<7168, 256, 0, stream>>>(Po, out);
}